// Round 21
// baseline (86.703 us; speedup 1.0000x reference)
//
#include <hip/hip_runtime.h>
#include <hip/hip_bf16.h>

#define Bn 8
#define Sn 2048
#define Dn 512
#define Kn 64

typedef _Float16 half8 __attribute__((ext_vector_type(8)));
typedef _Float16 half4v __attribute__((ext_vector_type(4)));
typedef __fp16 fp16x2 __attribute__((ext_vector_type(2)));
typedef float f32x4 __attribute__((ext_vector_type(4)));

#define MFMA16(a,b,c) __builtin_amdgcn_mfma_f32_16x16x32_f16(a,b,c,0,0,0)
#define LOG2E 1.4426950408889634f
#define EXP2(x) __builtin_amdgcn_exp2f(x)

__device__ __forceinline__ void glds16(const void* g, void* l){
    __builtin_amdgcn_global_load_lds(
        (const __attribute__((address_space(1))) unsigned int*)g,
        (__attribute__((address_space(3))) unsigned int*)l, 16, 0, 0);
}

// Fragment layouts in global memory (16B granules, lane = l4*16+l15):
//  Qh2/Kh2: granule (t*2+ks)*64+lane = M[t*16+l15][ks*32+l4*8 .. +8]   (t = global 16-row tile)
//  Vt2:     granule (((b*32+sc)*2+ks)*32+dt)*64+lane = V[dt*16+l15][sc*64+(ks*4+l4)*8 .. +8]
// Q pre-scaled by log2(e). Stats: Zp[qc][b][s] = sum_{q in chunk} 2^(l2-64).
// attn prologue folds csfin: CS[s] = -(64 + log2 sum_qc Zp) into LDS.
// attn: P[q,s] = 2^(l2[q,s] + CS[s]) via MFMA C-init; exp = raw v_exp_f32.
// attn blocks are 32q x 256d, 4 waves, grid 1024 -> 3+ barrier groups/CU.

// ---- Kernel 0: W transpose+cast ----
__global__ __launch_bounds__(256) void wtrans_kernel(
    const float* __restrict__ Wk, const float* __restrict__ Wq,
    _Float16* __restrict__ Wt16)
{
    const int n = blockIdx.x;
    const int t = threadIdx.x;
    const float* src = (n < 64) ? Wq : Wk;
    const int nn = n & 63;
    #pragma unroll
    for (int i = 0; i < 2; ++i){
        const int k = t + 256*i;
        Wt16[(size_t)n*Dn + k] = (_Float16)src[(size_t)k*Kn + nn];
    }
}

// ---- Kernel 1: fused Q/K projection + V transpose (32 rows per block) ----
__global__ __launch_bounds__(256, 2) void prep_kernel(
    const float* __restrict__ X, const _Float16* __restrict__ Wt16,
    const float* __restrict__ bk, const float* __restrict__ bq,
    _Float16* __restrict__ Qh2, _Float16* __restrict__ Kh2,
    _Float16* __restrict__ Vt2)
{
    __shared__ _Float16 Xt[2][32*64];
    const int bid = blockIdx.x;
    const int b = bid & 7, sb32 = bid >> 3;
    const int tid = threadIdx.x, lane = tid & 63, w = tid >> 6;
    const int l15 = lane & 15, l4 = lane >> 4;

    const int srow = tid >> 3, sg = tid & 7;
    const float* Xs = X + ((size_t)(b*Sn + sb32*32) + srow)*Dn + sg*8;
    const int sdst = srow*128 + (((sg ^ (srow & 7) ^ (srow >> 3)) & 7) * 16);

    const int n0 = w*32 + l15;
    const _Float16* Wp0 = Wt16 + (size_t)n0*Dn + l4*8;
    const _Float16* Wp1 = Wp0 + (size_t)16*Dn;

    f32x4 acc[2][2];
    #pragma unroll
    for (int i = 0; i < 2; ++i)
        #pragma unroll
        for (int j = 0; j < 2; ++j){ f32x4 z = {0.f,0.f,0.f,0.f}; acc[i][j] = z; }

    {
        const float4 v0 = *(const float4*)(Xs);
        const float4 v1 = *(const float4*)(Xs + 4);
        half8 h;
        h[0]=(_Float16)v0.x; h[1]=(_Float16)v0.y; h[2]=(_Float16)v0.z; h[3]=(_Float16)v0.w;
        h[4]=(_Float16)v1.x; h[5]=(_Float16)v1.y; h[6]=(_Float16)v1.z; h[7]=(_Float16)v1.w;
        *(half8*)((char*)Xt[0] + sdst) = h;
    }
    __syncthreads();

    const int dcol = w*16 + l15;
    #pragma unroll
    for (int kc = 0; kc < 8; ++kc){
        const _Float16* XtC = Xt[kc & 1];
        float4 nv0, nv1;
        if (kc < 7){
            nv0 = *(const float4*)(Xs + (kc+1)*64);
            nv1 = *(const float4*)(Xs + (kc+1)*64 + 4);
        }
        const half8 wf00 = *(const half8*)(Wp0 + kc*64);
        const half8 wf01 = *(const half8*)(Wp0 + kc*64 + 32);
        const half8 wf10 = *(const half8*)(Wp1 + kc*64);
        const half8 wf11 = *(const half8*)(Wp1 + kc*64 + 32);
        #pragma unroll
        for (int ks = 0; ks < 2; ++ks){
            #pragma unroll
            for (int qt = 0; qt < 2; ++qt){
                const int rw = qt*16 + l15;
                const int g = ((ks*4 + l4) ^ (rw & 7) ^ (rw >> 3)) & 7;
                const half8 a = *(const half8*)((const char*)XtC + rw*128 + g*16);
                acc[qt][0] = MFMA16(a, ks ? wf01 : wf00, acc[qt][0]);
                acc[qt][1] = MFMA16(a, ks ? wf11 : wf10, acc[qt][1]);
            }
        }
        {
            half8 hv;
            #pragma unroll
            for (int e = 0; e < 8; ++e){
                const int rw = l4*8 + e;
                const int g = ((dcol >> 3) ^ e ^ l4) & 7;
                hv[e] = XtC[rw*64 + g*8 + (dcol & 7)];
            }
            const size_t G = (((size_t)(b*32 + (sb32 >> 1))*2 + (sb32 & 1))*32 + kc*4 + w)*64 + lane;
            *(half8*)(Vt2 + G*8) = hv;
        }
        if (kc < 7){
            half8 h;
            h[0]=(_Float16)nv0.x; h[1]=(_Float16)nv0.y; h[2]=(_Float16)nv0.z; h[3]=(_Float16)nv0.w;
            h[4]=(_Float16)nv1.x; h[5]=(_Float16)nv1.y; h[6]=(_Float16)nv1.z; h[7]=(_Float16)nv1.w;
            *(half8*)((char*)Xt[(kc+1) & 1] + sdst) = h;
        }
        __syncthreads();
    }

    _Float16* tile16 = &Xt[0][0];
    #pragma unroll
    for (int qt = 0; qt < 2; ++qt){
        const int ql = qt*16 + l4*4;
        #pragma unroll
        for (int nt = 0; nt < 2; ++nt){
            const int n = w*32 + nt*16 + l15;
            const bool isQ = (n < 64);
            const float bias = isQ ? bq[n] : bk[n - 64];
            const float scale = isQ ? LOG2E : 1.0f;
            #pragma unroll
            for (int r = 0; r < 4; ++r)
                tile16[(ql + r)*128 + n] = (_Float16)((acc[qt][nt][r] + bias) * scale);
        }
    }
    __syncthreads();
    #pragma unroll
    for (int i = 0; i < 2; ++i){
        const int g = tid + 256*i;
        const int isK = g >> 8, qtl = (g >> 7) & 1, ks = (g >> 6) & 1, ln = g & 63;
        const int l4g = ln >> 4, l15g = ln & 15;
        const half8 h = *(const half8*)&tile16[(qtl*16 + l15g)*128 + isK*64 + ks*32 + l4g*8];
        const size_t tg = (size_t)b*128 + sb32*2 + qtl;
        _Float16* dst = (isK ? Kh2 : Qh2) + ((tg*2 + ks)*64 + ln)*8;
        *(half8*)dst = h;
    }
}

// ---- Kernel 2: stats — per-(b,s) partial denominators, Q staged in LDS ----
__global__ __launch_bounds__(512) void stats_kernel(
    const _Float16* __restrict__ Qh2, const _Float16* __restrict__ Kh2,
    float* __restrict__ Zp)
{
    __shared__ _Float16 Qs[256*64];   // 32 KB, fragment-linear
    const int bid = blockIdx.x;
    const int b = bid & 7, ss = (bid >> 3) & 3, qc = bid >> 5;
    const int tid = threadIdx.x, lane = tid & 63, w = tid >> 6;
    const int l15 = lane & 15, l4 = lane >> 4;

    const char* Qsrc = (const char*)Qh2 + (size_t)(b*128 + qc*16)*2048;
    #pragma unroll
    for (int i = 0; i < 4; ++i)
        glds16(Qsrc + tid*16 + i*8192, (char*)Qs + w*1024 + i*8192);

    half8 ka[4][2];
    const char* Kb = (const char*)Kh2 + (size_t)(b*128 + ss*32 + w*4)*2048 + lane*16;
    #pragma unroll
    for (int st = 0; st < 4; ++st)
        #pragma unroll
        for (int ks = 0; ks < 2; ++ks)
            ka[st][ks] = *(const half8*)(Kb + st*2048 + ks*1024);

    __syncthreads();

    const f32x4 cinit = {-64.f, -64.f, -64.f, -64.f};
    float z[4][4];
    #pragma unroll
    for (int st = 0; st < 4; ++st)
        #pragma unroll
        for (int r = 0; r < 4; ++r) z[st][r] = 0.f;

    const char* Qb = (const char*)Qs + lane*16;
    for (int qt = 0; qt < 16; ++qt){
        const half8 qb0 = *(const half8*)(Qb + qt*2048);
        const half8 qb1 = *(const half8*)(Qb + qt*2048 + 1024);
        #pragma unroll
        for (int st = 0; st < 4; ++st){
            f32x4 c = cinit;
            c = MFMA16(ka[st][0], qb0, c);
            c = MFMA16(ka[st][1], qb1, c);
            #pragma unroll
            for (int r = 0; r < 4; ++r)
                z[st][r] += EXP2(c[r]);
        }
    }
    #pragma unroll
    for (int d = 1; d < 16; d <<= 1)
        #pragma unroll
        for (int st = 0; st < 4; ++st)
            #pragma unroll
            for (int r = 0; r < 4; ++r)
                z[st][r] += __shfl_xor(z[st][r], d);
    if (l15 == 0){
        float* zp = Zp + (((size_t)(qc*8 + b)) << 11) + ss*512 + w*64 + l4*4;
        #pragma unroll
        for (int st = 0; st < 4; ++st)
            #pragma unroll
            for (int r = 0; r < 4; ++r)
                zp[st*16 + r] = z[st][r];
    }
}

// ---- Kernel 3: fused CS-finalize + logits -> P -> P@V; 4-wave 32q x 256d ----
#define WRP(PT, QT, C) do { \
    const float e0 = EXP2(C[0]); \
    const float e1 = EXP2(C[1]); \
    const float e2 = EXP2(C[2]); \
    const float e3 = EXP2(C[3]); \
    const fp16x2 plo = __builtin_amdgcn_cvt_pkrtz(e0, e1); \
    const fp16x2 phi = __builtin_amdgcn_cvt_pkrtz(e2, e3); \
    uint2 pu; \
    pu.x = __builtin_bit_cast(unsigned int, plo); \
    pu.y = __builtin_bit_cast(unsigned int, phi); \
    *(uint2*)((char*)(PT) + (QT)*2048 + pw_base) = pu; \
} while(0)

#define ABODY(KA, KAN, VB, VBN, CSA, CSN, PT) do { \
    f32x4 c0 = {CSA.x, CSA.y, CSA.z, CSA.w}; \
    f32x4 c1 = c0; \
    c0 = MFMA16(KA[0], qb[0][0], c0); c0 = MFMA16(KA[1], qb[0][1], c0); \
    c1 = MFMA16(KA[0], qb[1][0], c1); c1 = MFMA16(KA[1], qb[1][1], c1); \
    KAN[0] = *(const half8*)(Kp); \
    KAN[1] = *(const half8*)(Kp + 1024); \
    Kp += 8192; \
    CSN = *(const float4*)CSlp; CSlp += 64; \
    _Pragma("unroll") \
    for (int d_ = 0; d_ < 4; ++d_){ \
        VBN[d_]   = *(const half8*)(Vp0 + d_*1024); \
        VBN[4+d_] = *(const half8*)(Vp1 + d_*1024); \
    } \
    Vp0 += 65536; Vp1 += 65536; \
    WRP(PT, 0, c0); WRP(PT, 1, c1); \
    asm volatile("s_waitcnt lgkmcnt(0)\n\ts_barrier" ::: "memory"); \
    __builtin_amdgcn_s_setprio(1); \
    { const char* PB = (const char*)(PT); \
      _Pragma("unroll") \
      for (int ks = 0; ks < 2; ++ks){ \
        const int po = ks ? paoff1 : paoff0; \
        const half8 pa0 = *(const half8*)(PB + 0*2048 + po); \
        const half8 pa1 = *(const half8*)(PB + 1*2048 + po); \
        _Pragma("unroll") \
        for (int d_ = 0; d_ < 4; ++d_){ \
            acc[0][d_] = MFMA16(pa0, VB[ks*4+d_], acc[0][d_]); \
            acc[1][d_] = MFMA16(pa1, VB[ks*4+d_], acc[1][d_]); \
        } \
      } } \
    __builtin_amdgcn_s_setprio(0); \
} while(0)

__global__ __launch_bounds__(256, 3) void attn_kernel(
    const _Float16* __restrict__ Qh2, const _Float16* __restrict__ Kh2,
    const _Float16* __restrict__ Vt2, const float* __restrict__ Zp,
    float* __restrict__ out)
{
    __shared__ _Float16 Pt[2][32*64];   // 8 KB
    __shared__ float CSl[2176];         // 8.5 KB (pad for prefetch overrun)
    const int bid = blockIdx.x;
    const int b  = bid & 7;             // b-major -> one batch per XCD
    const int qi = (bid >> 3) & 63;     // 32-q tile
    const int dh = bid >> 9;            // 0..1 d-half
    const int q0 = qi * 32;
    const int tid = threadIdx.x, lane = tid & 63, w = tid >> 6;   // w 0..3
    const int l15 = lane & 15, l4 = lane >> 4;
    const int soff = w*16 + l4*4;       // s offset within tile (wave owns s-tile w)
    const int sb2  = soff * 2;
    const int pw_base = l15*128 + (sb2 ^ ((l15 & 7) << 4));
    const int paoff0  = l15*128 + ((l4 ^ (l15 & 7)) << 4);
    const int paoff1  = paoff0 ^ 64;

    // ---- folded csfin: CS for this batch into LDS ----
    {
        const float* zpp = Zp + ((size_t)b << 11) + tid;
        #pragma unroll
        for (int j = 0; j < 8; ++j){
            float zs = 0.f;
            #pragma unroll
            for (int qc = 0; qc < 8; ++qc)
                zs += zpp[(qc << 14) + j*256];
            CSl[tid + j*256] = -(64.0f + __log2f(zs));
        }
    }

    // Q fragments (2 qt x 2 ks)
    const size_t qgb = (size_t)b*128 + qi*2;
    half8 qb[2][2];
    #pragma unroll
    for (int qt = 0; qt < 2; ++qt)
        #pragma unroll
        for (int ks = 0; ks < 2; ++ks)
            qb[qt][ks] = *(const half8*)(Qh2 + (((qgb + qt)*2 + ks)*64 + lane)*8);

    // bumped pointers (point at next tile to fetch)
    const char* Kp  = (const char*)Kh2 + (size_t)(b*128 + w)*2048 + lane*16;
    const char* Vp0 = (const char*)Vt2 + (size_t)(b*2048 + dh*16 + w*4)*1024 + lane*16;
    const char* Vp1 = Vp0 + 32768;

    // prologue: prefetch sc=0 (K, V)
    half8 kaA[2], kaB[2], vbA[8], vbB[8];
    float4 csA, csB;
    kaA[0] = *(const half8*)(Kp);
    kaA[1] = *(const half8*)(Kp + 1024);
    Kp += 8192;
    #pragma unroll
    for (int d_ = 0; d_ < 4; ++d_){
        vbA[d_]   = *(const half8*)(Vp0 + d_*1024);
        vbA[4+d_] = *(const half8*)(Vp1 + d_*1024);
    }
    Vp0 += 65536; Vp1 += 65536;
    __syncthreads();                     // CSl visible
    const float* CSlp = CSl + soff;
    csA = *(const float4*)CSlp; CSlp += 64;

    f32x4 acc[2][4];
    #pragma unroll
    for (int i = 0; i < 2; ++i)
        #pragma unroll
        for (int j = 0; j < 4; ++j){ f32x4 zz4 = {0.f,0.f,0.f,0.f}; acc[i][j] = zz4; }

    for (int it = 0; it < 16; ++it){
        ABODY(kaA, kaB, vbA, vbB, csA, csB, Pt[0]);
        ABODY(kaB, kaA, vbB, vbA, csB, csA, Pt[1]);
    }

    float* ob = out + (size_t)(b*Sn + q0)*Dn + dh*256 + w*64;
    #pragma unroll
    for (int qt = 0; qt < 2; ++qt){
        const int q = qt*16 + l4*4;
        #pragma unroll
        for (int d_ = 0; d_ < 4; ++d_){
            #pragma unroll
            for (int r = 0; r < 4; ++r)
                ob[(size_t)(q + r)*Dn + d_*16 + l15] = acc[qt][d_][r];
        }
    }
}

extern "C" void kernel_launch(void* const* d_in, const int* in_sizes, int n_in,
                              void* d_out, int out_size, void* d_ws, size_t ws_size,
                              hipStream_t stream)
{
    const float* X  = (const float*)d_in[0];
    const float* Wk = (const float*)d_in[1];
    const float* bk = (const float*)d_in[2];
    const float* Wq = (const float*)d_in[3];
    const float* bq = (const float*)d_in[4];
    float* out = (float*)d_out;

    char* ws = (char*)d_ws;
    _Float16* Qh2  = (_Float16*)ws;                                  // 2 MB
    _Float16* Kh2  = (_Float16*)(ws + ((size_t)2 << 20));            // 2 MB
    _Float16* Vt2  = (_Float16*)(ws + ((size_t)4 << 20));            // 16 MB
    _Float16* Wt16 = (_Float16*)(ws + ((size_t)20 << 20) + (2 << 16)); // 128 KB
    float*    Zp   = (float*)(ws + ((size_t)21 << 20));              // 512 KB partials

    wtrans_kernel<<<dim3(128), dim3(256), 0, stream>>>(Wk, Wq, Wt16);
    prep_kernel<<<dim3(Bn*(Sn/32)), dim3(256), 0, stream>>>(X, Wt16, bk, bq, Qh2, Kh2, Vt2);
    stats_kernel<<<dim3(256), dim3(512), 0, stream>>>(Qh2, Kh2, Zp);
    attn_kernel<<<dim3(Bn*(Sn/32)*2), dim3(256), 0, stream>>>(Qh2, Kh2, Vt2, Zp, out);
}

// Round 22
// 67.623 us; speedup vs baseline: 1.2821x; 1.2821x over previous
//
#include <hip/hip_runtime.h>
#include <hip/hip_bf16.h>

#define Bn 8
#define Sn 2048
#define Dn 512
#define Kn 64

typedef _Float16 half8 __attribute__((ext_vector_type(8)));
typedef _Float16 half4v __attribute__((ext_vector_type(4)));
typedef __fp16 fp16x2 __attribute__((ext_vector_type(2)));
typedef float f32x4 __attribute__((ext_vector_type(4)));

#define MFMA16(a,b,c) __builtin_amdgcn_mfma_f32_16x16x32_f16(a,b,c,0,0,0)
#define LOG2E 1.4426950408889634f
#define EXP2(x) __builtin_amdgcn_exp2f(x)

__device__ __forceinline__ void glds16(const void* g, void* l){
    __builtin_amdgcn_global_load_lds(
        (const __attribute__((address_space(1))) unsigned int*)g,
        (__attribute__((address_space(3))) unsigned int*)l, 16, 0, 0);
}

// Fragment layouts in global memory (16B granules, lane = l4*16+l15):
//  Qh2/Kh2: granule (t*2+ks)*64+lane = M[t*16+l15][ks*32+l4*8 .. +8]   (t = global 16-row tile)
//  Vt2:     granule (((b*32+sc)*2+ks)*32+dt)*64+lane = V[dt*16+l15][sc*64+(ks*4+l4)*8 .. +8]
// Q pre-scaled by log2(e). Stats: Zp[qc][b][s] = sum_{q in chunk} 2^(l2-64).
// attn prologue folds csfin: CS[s] = -(64 + log2 sum_qc Zp) computed into LDS.
// attn: P[q,s] = 2^(l2[q,s] + CS[s]) via MFMA C-init; exp = raw v_exp_f32.

// ---- Kernel 0: W transpose+cast ----
__global__ __launch_bounds__(256) void wtrans_kernel(
    const float* __restrict__ Wk, const float* __restrict__ Wq,
    _Float16* __restrict__ Wt16)
{
    const int n = blockIdx.x;
    const int t = threadIdx.x;
    const float* src = (n < 64) ? Wq : Wk;
    const int nn = n & 63;
    #pragma unroll
    for (int i = 0; i < 2; ++i){
        const int k = t + 256*i;
        Wt16[(size_t)n*Dn + k] = (_Float16)src[(size_t)k*Kn + nn];
    }
}

// ---- Kernel 1: fused Q/K projection + V transpose (32 rows per block) ----
__global__ __launch_bounds__(256, 2) void prep_kernel(
    const float* __restrict__ X, const _Float16* __restrict__ Wt16,
    const float* __restrict__ bk, const float* __restrict__ bq,
    _Float16* __restrict__ Qh2, _Float16* __restrict__ Kh2,
    _Float16* __restrict__ Vt2)
{
    __shared__ _Float16 Xt[2][32*64];
    const int bid = blockIdx.x;
    const int b = bid & 7, sb32 = bid >> 3;
    const int tid = threadIdx.x, lane = tid & 63, w = tid >> 6;
    const int l15 = lane & 15, l4 = lane >> 4;

    const int srow = tid >> 3, sg = tid & 7;
    const float* Xs = X + ((size_t)(b*Sn + sb32*32) + srow)*Dn + sg*8;
    const int sdst = srow*128 + (((sg ^ (srow & 7) ^ (srow >> 3)) & 7) * 16);

    const int n0 = w*32 + l15;
    const _Float16* Wp0 = Wt16 + (size_t)n0*Dn + l4*8;
    const _Float16* Wp1 = Wp0 + (size_t)16*Dn;

    f32x4 acc[2][2];
    #pragma unroll
    for (int i = 0; i < 2; ++i)
        #pragma unroll
        for (int j = 0; j < 2; ++j){ f32x4 z = {0.f,0.f,0.f,0.f}; acc[i][j] = z; }

    {
        const float4 v0 = *(const float4*)(Xs);
        const float4 v1 = *(const float4*)(Xs + 4);
        half8 h;
        h[0]=(_Float16)v0.x; h[1]=(_Float16)v0.y; h[2]=(_Float16)v0.z; h[3]=(_Float16)v0.w;
        h[4]=(_Float16)v1.x; h[5]=(_Float16)v1.y; h[6]=(_Float16)v1.z; h[7]=(_Float16)v1.w;
        *(half8*)((char*)Xt[0] + sdst) = h;
    }
    __syncthreads();

    const int dcol = w*16 + l15;
    #pragma unroll
    for (int kc = 0; kc < 8; ++kc){
        const _Float16* XtC = Xt[kc & 1];
        float4 nv0, nv1;
        if (kc < 7){
            nv0 = *(const float4*)(Xs + (kc+1)*64);
            nv1 = *(const float4*)(Xs + (kc+1)*64 + 4);
        }
        const half8 wf00 = *(const half8*)(Wp0 + kc*64);
        const half8 wf01 = *(const half8*)(Wp0 + kc*64 + 32);
        const half8 wf10 = *(const half8*)(Wp1 + kc*64);
        const half8 wf11 = *(const half8*)(Wp1 + kc*64 + 32);
        #pragma unroll
        for (int ks = 0; ks < 2; ++ks){
            #pragma unroll
            for (int qt = 0; qt < 2; ++qt){
                const int rw = qt*16 + l15;
                const int g = ((ks*4 + l4) ^ (rw & 7) ^ (rw >> 3)) & 7;
                const half8 a = *(const half8*)((const char*)XtC + rw*128 + g*16);
                acc[qt][0] = MFMA16(a, ks ? wf01 : wf00, acc[qt][0]);
                acc[qt][1] = MFMA16(a, ks ? wf11 : wf10, acc[qt][1]);
            }
        }
        {
            half8 hv;
            #pragma unroll
            for (int e = 0; e < 8; ++e){
                const int rw = l4*8 + e;
                const int g = ((dcol >> 3) ^ e ^ l4) & 7;
                hv[e] = XtC[rw*64 + g*8 + (dcol & 7)];
            }
            const size_t G = (((size_t)(b*32 + (sb32 >> 1))*2 + (sb32 & 1))*32 + kc*4 + w)*64 + lane;
            *(half8*)(Vt2 + G*8) = hv;
        }
        if (kc < 7){
            half8 h;
            h[0]=(_Float16)nv0.x; h[1]=(_Float16)nv0.y; h[2]=(_Float16)nv0.z; h[3]=(_Float16)nv0.w;
            h[4]=(_Float16)nv1.x; h[5]=(_Float16)nv1.y; h[6]=(_Float16)nv1.z; h[7]=(_Float16)nv1.w;
            *(half8*)((char*)Xt[(kc+1) & 1] + sdst) = h;
        }
        __syncthreads();
    }

    _Float16* tile16 = &Xt[0][0];
    #pragma unroll
    for (int qt = 0; qt < 2; ++qt){
        const int ql = qt*16 + l4*4;
        #pragma unroll
        for (int nt = 0; nt < 2; ++nt){
            const int n = w*32 + nt*16 + l15;
            const bool isQ = (n < 64);
            const float bias = isQ ? bq[n] : bk[n - 64];
            const float scale = isQ ? LOG2E : 1.0f;
            #pragma unroll
            for (int r = 0; r < 4; ++r)
                tile16[(ql + r)*128 + n] = (_Float16)((acc[qt][nt][r] + bias) * scale);
        }
    }
    __syncthreads();
    #pragma unroll
    for (int i = 0; i < 2; ++i){
        const int g = tid + 256*i;
        const int isK = g >> 8, qtl = (g >> 7) & 1, ks = (g >> 6) & 1, ln = g & 63;
        const int l4g = ln >> 4, l15g = ln & 15;
        const half8 h = *(const half8*)&tile16[(qtl*16 + l15g)*128 + isK*64 + ks*32 + l4g*8];
        const size_t tg = (size_t)b*128 + sb32*2 + qtl;
        _Float16* dst = (isK ? Kh2 : Qh2) + ((tg*2 + ks)*64 + ln)*8;
        *(half8*)dst = h;
    }
}

// ---- Kernel 2: stats — per-(b,s) partial denominators, Q staged in LDS ----
__global__ __launch_bounds__(512) void stats_kernel(
    const _Float16* __restrict__ Qh2, const _Float16* __restrict__ Kh2,
    float* __restrict__ Zp)
{
    __shared__ _Float16 Qs[256*64];   // 32 KB, fragment-linear
    const int bid = blockIdx.x;
    const int b = bid & 7, ss = (bid >> 3) & 3, qc = bid >> 5;
    const int tid = threadIdx.x, lane = tid & 63, w = tid >> 6;
    const int l15 = lane & 15, l4 = lane >> 4;

    const char* Qsrc = (const char*)Qh2 + (size_t)(b*128 + qc*16)*2048;
    #pragma unroll
    for (int i = 0; i < 4; ++i)
        glds16(Qsrc + tid*16 + i*8192, (char*)Qs + w*1024 + i*8192);

    half8 ka[4][2];
    const char* Kb = (const char*)Kh2 + (size_t)(b*128 + ss*32 + w*4)*2048 + lane*16;
    #pragma unroll
    for (int st = 0; st < 4; ++st)
        #pragma unroll
        for (int ks = 0; ks < 2; ++ks)
            ka[st][ks] = *(const half8*)(Kb + st*2048 + ks*1024);

    __syncthreads();

    const f32x4 cinit = {-64.f, -64.f, -64.f, -64.f};
    float z[4][4];
    #pragma unroll
    for (int st = 0; st < 4; ++st)
        #pragma unroll
        for (int r = 0; r < 4; ++r) z[st][r] = 0.f;

    const char* Qb = (const char*)Qs + lane*16;
    for (int qt = 0; qt < 16; ++qt){
        const half8 qb0 = *(const half8*)(Qb + qt*2048);
        const half8 qb1 = *(const half8*)(Qb + qt*2048 + 1024);
        #pragma unroll
        for (int st = 0; st < 4; ++st){
            f32x4 c = cinit;
            c = MFMA16(ka[st][0], qb0, c);
            c = MFMA16(ka[st][1], qb1, c);
            #pragma unroll
            for (int r = 0; r < 4; ++r)
                z[st][r] += EXP2(c[r]);
        }
    }
    #pragma unroll
    for (int d = 1; d < 16; d <<= 1)
        #pragma unroll
        for (int st = 0; st < 4; ++st)
            #pragma unroll
            for (int r = 0; r < 4; ++r)
                z[st][r] += __shfl_xor(z[st][r], d);
    if (l15 == 0){
        float* zp = Zp + (((size_t)(qc*8 + b)) << 11) + ss*512 + w*64 + l4*4;
        #pragma unroll
        for (int st = 0; st < 4; ++st)
            #pragma unroll
            for (int r = 0; r < 4; ++r)
                zp[st*16 + r] = z[st][r];
    }
}

// ---- Kernel 3: fused CS-finalize + logits -> P -> P@V; 4-wave 64q x 256d ----
#define WRP(PT, QT, C) do { \
    const float e0 = EXP2(C[0]); \
    const float e1 = EXP2(C[1]); \
    const float e2 = EXP2(C[2]); \
    const float e3 = EXP2(C[3]); \
    const fp16x2 plo = __builtin_amdgcn_cvt_pkrtz(e0, e1); \
    const fp16x2 phi = __builtin_amdgcn_cvt_pkrtz(e2, e3); \
    uint2 pu; \
    pu.x = __builtin_bit_cast(unsigned int, plo); \
    pu.y = __builtin_bit_cast(unsigned int, phi); \
    *(uint2*)((char*)(PT) + (QT)*2048 + pw_base) = pu; \
} while(0)

#define ABODY(KA, KAN, VB, VBN, CSA, CSN, PT) do { \
    f32x4 c0 = {CSA.x, CSA.y, CSA.z, CSA.w}; \
    f32x4 c1 = c0, c2 = c0, c3 = c0; \
    c0 = MFMA16(KA[0], qb[0][0], c0); c0 = MFMA16(KA[1], qb[0][1], c0); \
    c1 = MFMA16(KA[0], qb[1][0], c1); c1 = MFMA16(KA[1], qb[1][1], c1); \
    c2 = MFMA16(KA[0], qb[2][0], c2); c2 = MFMA16(KA[1], qb[2][1], c2); \
    c3 = MFMA16(KA[0], qb[3][0], c3); c3 = MFMA16(KA[1], qb[3][1], c3); \
    KAN[0] = *(const half8*)(Kp); \
    KAN[1] = *(const half8*)(Kp + 1024); \
    Kp += 8192; \
    CSN = *(const float4*)CSlp; CSlp += 64; \
    _Pragma("unroll") \
    for (int d_ = 0; d_ < 4; ++d_){ \
        VBN[d_]   = *(const half8*)(Vp0 + d_*1024); \
        VBN[4+d_] = *(const half8*)(Vp1 + d_*1024); \
    } \
    Vp0 += 65536; Vp1 += 65536; \
    WRP(PT, 0, c0); WRP(PT, 1, c1); \
    WRP(PT, 2, c2); WRP(PT, 3, c3); \
    asm volatile("s_waitcnt lgkmcnt(0)\n\ts_barrier" ::: "memory"); \
    __builtin_amdgcn_s_setprio(1); \
    { const char* PB = (const char*)(PT); \
      _Pragma("unroll") \
      for (int ks = 0; ks < 2; ++ks){ \
        const int po = ks ? paoff1 : paoff0; \
        const half8 pa0 = *(const half8*)(PB + 0*2048 + po); \
        const half8 pa1 = *(const half8*)(PB + 1*2048 + po); \
        const half8 pa2 = *(const half8*)(PB + 2*2048 + po); \
        const half8 pa3 = *(const half8*)(PB + 3*2048 + po); \
        _Pragma("unroll") \
        for (int d_ = 0; d_ < 4; ++d_){ \
            acc[0][d_] = MFMA16(pa0, VB[ks*4+d_], acc[0][d_]); \
            acc[1][d_] = MFMA16(pa1, VB[ks*4+d_], acc[1][d_]); \
            acc[2][d_] = MFMA16(pa2, VB[ks*4+d_], acc[2][d_]); \
            acc[3][d_] = MFMA16(pa3, VB[ks*4+d_], acc[3][d_]); \
        } \
      } } \
    __builtin_amdgcn_s_setprio(0); \
} while(0)

__global__ __launch_bounds__(256, 2) void attn_kernel(
    const _Float16* __restrict__ Qh2, const _Float16* __restrict__ Kh2,
    const _Float16* __restrict__ Vt2, const float* __restrict__ Zp,
    float* __restrict__ out)
{
    __shared__ _Float16 Pt[2][64*64];   // 16 KB
    __shared__ float CSl[2176];         // 8.5 KB (64+ float pad for prefetch overrun)
    const int bid = blockIdx.x;
    const int b  = bid & 7;             // b-major -> one batch per XCD
    const int qi = (bid >> 3) & 31;
    const int dh = bid >> 8;            // 0..1 d-half
    const int q0 = qi * 64;
    const int tid = threadIdx.x, lane = tid & 63, w = tid >> 6;   // w 0..3
    const int l15 = lane & 15, l4 = lane >> 4;
    const int soff = w*16 + l4*4;
    const int sb2  = soff * 2;
    const int pw_base = l15*128 + (sb2 ^ ((l15 & 7) << 4));
    const int paoff0  = l15*128 + ((l4 ^ (l15 & 7)) << 4);
    const int paoff1  = paoff0 ^ 64;

    // ---- folded csfin: CS for this batch into LDS ----
    {
        const float* zpp = Zp + ((size_t)b << 11) + tid;
        #pragma unroll
        for (int j = 0; j < 8; ++j){
            float zs = 0.f;
            #pragma unroll
            for (int qc = 0; qc < 8; ++qc)
                zs += zpp[(qc << 14) + j*256];
            CSl[tid + j*256] = -(64.0f + __log2f(zs));
        }
    }

    // Q fragments (held whole kernel)
    const size_t qgb = (size_t)b*128 + qi*4;
    half8 qb[4][2];
    #pragma unroll
    for (int qt = 0; qt < 4; ++qt)
        #pragma unroll
        for (int ks = 0; ks < 2; ++ks)
            qb[qt][ks] = *(const half8*)(Qh2 + (((qgb + qt)*2 + ks)*64 + lane)*8);

    // bumped pointers (point at next tile to fetch)
    const char* Kp  = (const char*)Kh2 + (size_t)(b*128 + w)*2048 + lane*16;
    const char* Vp0 = (const char*)Vt2 + (size_t)(b*2048 + dh*16 + w*4)*1024 + lane*16;
    const char* Vp1 = Vp0 + 32768;

    // prologue: prefetch sc=0 (K, V); CS needs the sync first
    half8 kaA[2], kaB[2], vbA[8], vbB[8];
    float4 csA, csB;
    kaA[0] = *(const half8*)(Kp);
    kaA[1] = *(const half8*)(Kp + 1024);
    Kp += 8192;
    #pragma unroll
    for (int d_ = 0; d_ < 4; ++d_){
        vbA[d_]   = *(const half8*)(Vp0 + d_*1024);
        vbA[4+d_] = *(const half8*)(Vp1 + d_*1024);
    }
    Vp0 += 65536; Vp1 += 65536;
    __syncthreads();                     // CSl visible
    const float* CSlp = CSl + soff;
    csA = *(const float4*)CSlp; CSlp += 64;

    f32x4 acc[4][4];
    #pragma unroll
    for (int i = 0; i < 4; ++i)
        #pragma unroll
        for (int j = 0; j < 4; ++j){ f32x4 zz4 = {0.f,0.f,0.f,0.f}; acc[i][j] = zz4; }

    for (int it = 0; it < 16; ++it){
        ABODY(kaA, kaB, vbA, vbB, csA, csB, Pt[0]);
        ABODY(kaB, kaA, vbB, vbA, csB, csA, Pt[1]);
    }

    float* ob = out + (size_t)(b*Sn + q0)*Dn + dh*256 + w*64;
    #pragma unroll
    for (int qt = 0; qt < 4; ++qt){
        const int q = qt*16 + l4*4;
        #pragma unroll
        for (int d_ = 0; d_ < 4; ++d_){
            #pragma unroll
            for (int r = 0; r < 4; ++r)
                ob[(size_t)(q + r)*Dn + d_*16 + l15] = acc[qt][d_][r];
        }
    }
}

extern "C" void kernel_launch(void* const* d_in, const int* in_sizes, int n_in,
                              void* d_out, int out_size, void* d_ws, size_t ws_size,
                              hipStream_t stream)
{
    const float* X  = (const float*)d_in[0];
    const float* Wk = (const float*)d_in[1];
    const float* bk = (const float*)d_in[2];
    const float* Wq = (const float*)d_in[3];
    const float* bq = (const float*)d_in[4];
    float* out = (float*)d_out;

    char* ws = (char*)d_ws;
    _Float16* Qh2  = (_Float16*)ws;                                  // 2 MB
    _Float16* Kh2  = (_Float16*)(ws + ((size_t)2 << 20));            // 2 MB
    _Float16* Vt2  = (_Float16*)(ws + ((size_t)4 << 20));            // 16 MB
    _Float16* Wt16 = (_Float16*)(ws + ((size_t)20 << 20) + (2 << 16)); // 128 KB
    float*    Zp   = (float*)(ws + ((size_t)21 << 20));              // 512 KB partials

    wtrans_kernel<<<dim3(128), dim3(256), 0, stream>>>(Wk, Wq, Wt16);
    prep_kernel<<<dim3(Bn*(Sn/32)), dim3(256), 0, stream>>>(X, Wt16, bk, bq, Qh2, Kh2, Vt2);
    stats_kernel<<<dim3(256), dim3(512), 0, stream>>>(Qh2, Kh2, Zp);
    attn_kernel<<<dim3(Bn*(Sn/64)*2), dim3(256), 0, stream>>>(Qh2, Kh2, Vt2, Zp, out);
}